// Round 10
// baseline (1527.676 us; speedup 1.0000x reference)
//
#include <hip/hip_runtime.h>
#include <hip/hip_fp16.h>
#include <math.h>

#define LQ 21760
#define NB 2
// levels: (16,16),(32,32),(64,64),(128,128); bases 0,256,1280,5376

typedef __attribute__((ext_vector_type(8))) short bf16x8;
typedef __attribute__((ext_vector_type(4))) float f32x4;

static __device__ __forceinline__ float wave_sum(float v) {
#pragma unroll
    for (int o = 32; o > 0; o >>= 1) v += __shfl_down(v, o, 64);
    return v;
}

static __device__ __forceinline__ unsigned short f2bf(float f) {
    unsigned int u = __float_as_uint(f);
    u = (u + 0x7fffu + ((u >> 16) & 1u)) >> 16;
    return (unsigned short)u;
}
static __device__ __forceinline__ float bf2f(unsigned short h) {
    return __uint_as_float((unsigned int)h << 16);
}
static __device__ __forceinline__ unsigned short f2h(float f) {
    __half h = __float2half(f);
    return *(unsigned short*)&h;
}

// async global->LDS 16B (linear dest: wave-uniform base + lane*16)
static __device__ __forceinline__ void gload16(const void* g, void* l) {
    __builtin_amdgcn_global_load_lds(
        (const __attribute__((address_space(1))) unsigned int*)g,
        (__attribute__((address_space(3))) unsigned int*)l, 16, 0, 0);
}

__global__ __launch_bounds__(256) void zero_buf(float* __restrict__ p, int n) {
    const int i = blockIdx.x * 256 + threadIdx.x;
    if (i < n) p[i] = 0.f;
}

__global__ __launch_bounds__(256) void bias_cat(const float* __restrict__ boff,
                                                const float* __restrict__ battn,
                                                float* __restrict__ out) {
    const int idx = blockIdx.x * 256 + threadIdx.x;
    if (idx >= 3 * 192) return;
    const int l = idx / 192, i = idx - l * 192;
    out[idx] = (i < 128) ? boff[l * 128 + i] : battn[l * 64 + (i - 128)];
}

__global__ __launch_bounds__(256) void cvt_bf(const float* __restrict__ in,
                                              unsigned short* __restrict__ out, long n) {
    const long i = (long)blockIdx.x * 256 + threadIdx.x;
    if (i < n) out[i] = f2bf(in[i]);
}

// transpose + cvt: in (Kr x Nc) fp32 -> out (Nc x Kr) bf16. grid (Nc/32, Kr/32)
__global__ __launch_bounds__(256) void transpose_cvt(const float* __restrict__ in,
                                                     unsigned short* __restrict__ out,
                                                     int Kr, int Nc)
{
    __shared__ float t[32][33];
    const int n0 = blockIdx.x * 32, k0 = blockIdx.y * 32;
    const int c = threadIdx.x & 31, r8 = threadIdx.x >> 5;
#pragma unroll
    for (int j = 0; j < 4; ++j) {
        const int r = r8 + j * 8;
        t[r][c] = in[(long)(k0 + r) * Nc + n0 + c];
    }
    __syncthreads();
#pragma unroll
    for (int j = 0; j < 4; ++j) {
        const int r = r8 + j * 8;
        out[(long)(n0 + r) * Kr + k0 + c] = f2bf(t[c][r]);
    }
}

// batch transpose+cvt: in (B, C, HW) fp32 -> out (B, HW, C) bf16. grid (HW/32, C/32, B)
__global__ __launch_bounds__(256) void transpose_cvt_x(const float* __restrict__ in,
                                                       unsigned short* __restrict__ out,
                                                       int C, int HW)
{
    __shared__ float t[32][33];
    const int hw0 = blockIdx.x * 32, c0 = blockIdx.y * 32;
    const int b = blockIdx.z;
    in  += (long)b * C * HW;
    out += (long)b * HW * C;
    const int cc = threadIdx.x & 31, rr = threadIdx.x >> 5;
#pragma unroll
    for (int j = 0; j < 4; ++j) {
        const int r = rr + j * 8;
        t[r][cc] = in[(long)(c0 + r) * HW + hw0 + cc];
    }
    __syncthreads();
#pragma unroll
    for (int j = 0; j < 4; ++j) {
        const int r = rr + j * 8;
        out[(long)(hw0 + r) * C + c0 + cc] = f2bf(t[cc][r]);
    }
}

// ---------------- bf16 MFMA GEMM: C(MxN) = A(MxK) @ Bt(NxK)^T ---------------
// A row-major bf16 (lda=K), Bt row-major bf16 (N x K). BM=128, BK=64.
// LDS: linear physical layout (global_load_lds) + XOR swizzle:
//   logical (row, colbyte) stored at physical row*128 + (colbyte ^ ((row&7)<<4))
// Outputs: Cf fp32, Cb (bf16 or fp16 per out_half), Cq = bf16(v + pos) fused q.
template<int BN>
__global__ __launch_bounds__(256) void gemm_bf(
    const unsigned short* __restrict__ A, const unsigned short* __restrict__ Bt, int K,
    float* __restrict__ Cf, unsigned short* __restrict__ Cb, int ldc,
    const float* __restrict__ bias, int relu, int out_half,
    unsigned short* __restrict__ Cq, const unsigned short* __restrict__ posb)
{
    constexpr int BM = 128, BK = 64;
    constexpr int BINST = (BN == 128) ? 4 : 2;   // 1KB gload insts per wave for B
    __shared__ unsigned short As[BM * BK];
    __shared__ unsigned short Bs[BN * BK];
    const int tid = threadIdx.x;
    const long m0 = (long)blockIdx.y * BM;
    const int n0 = blockIdx.x * BN;
    const int wave = tid >> 6, lane = tid & 63;
    constexpr int WM = (BN == 128) ? 2 : 4;
    constexpr int FM = (BN == 128) ? 4 : 2;
    const int wm = wave % WM, wn = wave / WM;
    const int wm0 = wm * (BM / WM), wn0 = wn * 64;
    const int lrow = lane & 15, lk8 = (lane >> 4) * 8;
    const int axor = (lrow & 7) << 4;            // read-side swizzle (uniform per lane)
    f32x4 acc[FM][4] = {};
    // staging source coords: physical byte p -> row p>>7, logical colbyte (p&127)^((row&7)<<4)
    int arow[4], acolb[4], brow[BINST], bcolb[BINST];
#pragma unroll
    for (int j = 0; j < 4; ++j) {
        const int p = (wave * 4 + j) * 1024 + lane * 16;
        const int r = p >> 7;
        arow[j] = r;
        acolb[j] = (p & 127) ^ ((r & 7) << 4);
    }
#pragma unroll
    for (int j = 0; j < BINST; ++j) {
        const int p = (wave * BINST + j) * 1024 + lane * 16;
        const int r = p >> 7;
        brow[j] = r;
        bcolb[j] = (p & 127) ^ ((r & 7) << 4);
    }
    for (int k0 = 0; k0 < K; k0 += BK) {
        __syncthreads();
#pragma unroll
        for (int j = 0; j < 4; ++j)
            gload16(A + (m0 + arow[j]) * (long)K + k0 + (acolb[j] >> 1),
                    (char*)As + (wave * 4 + j) * 1024 + lane * 16);
#pragma unroll
        for (int j = 0; j < BINST; ++j)
            gload16(Bt + (long)(n0 + brow[j]) * K + k0 + (bcolb[j] >> 1),
                    (char*)Bs + (wave * BINST + j) * 1024 + lane * 16);
        __syncthreads();
        bf16x8 af[FM][2], bfr[4][2];
#pragma unroll
        for (int i = 0; i < FM; ++i)
#pragma unroll
            for (int kk = 0; kk < 2; ++kk) {
                const int row = wm0 + i * 16 + lrow;
                const int cb = ((kk * 32 + lk8) << 1) ^ axor;
                af[i][kk] = *(const bf16x8*)((const char*)As + (row << 7) + cb);
            }
#pragma unroll
        for (int j = 0; j < 4; ++j)
#pragma unroll
            for (int kk = 0; kk < 2; ++kk) {
                const int row = wn0 + j * 16 + lrow;
                const int cb = ((kk * 32 + lk8) << 1) ^ axor;
                bfr[j][kk] = *(const bf16x8*)((const char*)Bs + (row << 7) + cb);
            }
#pragma unroll
        for (int i = 0; i < FM; ++i)
#pragma unroll
            for (int j = 0; j < 4; ++j)
#pragma unroll
                for (int kk = 0; kk < 2; ++kk)
                    acc[i][j] = __builtin_amdgcn_mfma_f32_16x16x32_bf16(
                        af[i][kk], bfr[j][kk], acc[i][j], 0, 0, 0);
    }
    const int rbase = (lane >> 4) * 4;
#pragma unroll
    for (int i = 0; i < FM; ++i) {
#pragma unroll
        for (int j = 0; j < 4; ++j) {
            const int col = n0 + wn0 + j * 16 + lrow;
            const float bb = bias ? bias[col] : 0.f;
#pragma unroll
            for (int r = 0; r < 4; ++r) {
                float v = acc[i][j][r] + bb;
                if (relu) v = fmaxf(v, 0.f);
                const long row = m0 + wm0 + i * 16 + rbase + r;
                const long idx = row * (long)ldc + col;
                if (Cf) Cf[idx] = v;
                if (Cb) Cb[idx] = out_half ? f2h(v) : f2bf(v);
                if (Cq) Cq[idx] = f2bf(v + bf2f(posb[row * 256 + col]));
            }
        }
    }
}

// ---------------- sine pos + level embed -> bf16 table ----------------------
__global__ __launch_bounds__(256) void pos_kernel(unsigned short* __restrict__ pos,
                                                  const float* __restrict__ lvl_emb)
{
    const int idx = blockIdx.x * 256 + threadIdx.x;  // < LQ*256
    const int d = idx & 255;
    const int i = idx >> 8;
    int lv, sz;
    if (i < 256)       { lv = 0; sz = 16; }
    else if (i < 1280) { lv = 1; sz = 32; }
    else if (i < 5376) { lv = 2; sz = 64; }
    else               { lv = 3; sz = 128; }
    const int base = (lv == 0) ? 0 : (lv == 1) ? 256 : (lv == 2) ? 1280 : 5376;
    const int hw = i - base;
    const int hy = hw / sz, wx = hw - hy * sz;
    const int dd = d & 127;
    const float twopi = 6.283185307179586f;
    const float e = ((d < 128) ? (float)(hy + 1) : (float)(wx + 1))
                    / ((float)sz + 1e-6f) * twopi;
    const float t = powf(10000.0f, (float)(2 * (dd >> 1)) * (1.0f / 128.0f));
    const float p = e / t;
    const float v = (dd & 1) ? cosf(p) : sinf(p);
    pos[idx] = f2bf(v + lvl_emb[lv * 256 + d]);
}

// ---------------- q = src_bf + pos (bf16, vectorized x4), layer 0 only ------
__global__ __launch_bounds__(256) void make_q2(const unsigned short* __restrict__ src_bf,
                                               const unsigned short* __restrict__ pos,
                                               unsigned short* __restrict__ q, long total4)
{
    const long t = (long)blockIdx.x * 256 + threadIdx.x;
    if (t >= total4) return;
    const long idx = t * 4;
    const long pe = (idx >= (long)LQ * 256) ? idx - (long)LQ * 256 : idx;
    const ushort4 s = *(const ushort4*)(src_bf + idx);
    const ushort4 pp = *(const ushort4*)(pos + pe);
    unsigned short o[4] = {f2bf(bf2f(s.x) + bf2f(pp.x)), f2bf(bf2f(s.y) + bf2f(pp.y)),
                           f2bf(bf2f(s.z) + bf2f(pp.z)), f2bf(bf2f(s.w) + bf2f(pp.w))};
    *(ushort4*)(q + idx) = *(const ushort4*)o;
}

// ---------------- group-norm stats on (B,HW,256) layout ---------------------
__global__ __launch_bounds__(256) void gn_stats2(const float* __restrict__ z,
                                                 float* __restrict__ stats,
                                                 int HW, int span)
{
    const int b = blockIdx.y;
    const int hw0 = blockIdx.x * span;
    const int d = threadIdx.x;
    float s = 0.f, sq = 0.f;
    const float* p = z + ((long)b * HW + hw0) * 256 + d;
    for (int i = 0; i < span; ++i) {
        const float v = p[(long)i * 256];
        s += v; sq += v * v;
    }
#pragma unroll
    for (int o = 1; o < 8; o <<= 1) {
        s += __shfl_xor(s, o, 64);
        sq += __shfl_xor(sq, o, 64);
    }
    if ((d & 7) == 0) {
        atomicAdd(&stats[(b * 32 + (d >> 3)) * 2 + 0], s);
        atomicAdd(&stats[(b * 32 + (d >> 3)) * 2 + 1], sq);
    }
}

// ---------------- group-norm scale (B,HW,256) -> src fp32 + bf16 ------------
__global__ __launch_bounds__(256) void gn_scale(const float* __restrict__ z,
                                                float* __restrict__ src,
                                                unsigned short* __restrict__ src_bf,
                                                const float* __restrict__ stats,
                                                const float* __restrict__ gg,
                                                const float* __restrict__ gb,
                                                int hwShift, int lvl_base, long total4)
{
    const long t = (long)blockIdx.x * 256 + threadIdx.x;
    if (t >= total4) return;
    const int d4 = (int)(t & 63) * 4;
    const long row = t >> 6;                       // b*HW + hw
    const int b = (int)(row >> hwShift);
    const int hw = (int)(row & ((1 << hwShift) - 1));
    const int g = d4 >> 3;
    const float s = stats[(b * 32 + g) * 2 + 0];
    const float sq = stats[(b * 32 + g) * 2 + 1];
    const float cnt = 8.0f * (float)(1 << hwShift);
    const float m = s / cnt;
    const float rstd = rsqrtf(sq / cnt - m * m + 1e-5f);
    const float4 v = *(const float4*)(z + row * 256 + d4);
    float o[4];
    o[0] = (v.x - m) * rstd * gg[d4 + 0] + gb[d4 + 0];
    o[1] = (v.y - m) * rstd * gg[d4 + 1] + gb[d4 + 1];
    o[2] = (v.z - m) * rstd * gg[d4 + 2] + gb[d4 + 2];
    o[3] = (v.w - m) * rstd * gg[d4 + 3] + gb[d4 + 3];
    const long oidx = ((long)b * LQ + lvl_base + hw) * 256 + d4;
    *(float4*)(src + oidx) = make_float4(o[0], o[1], o[2], o[3]);
    unsigned short ob[4] = {f2bf(o[0]), f2bf(o[1]), f2bf(o[2]), f2bf(o[3])};
    *(ushort4*)(src_bf + oidx) = *(const ushort4*)ob;
}

// ---------------- softmax over 16 bf16 at oa[row*192 + 128 + part*16] -------
__global__ __launch_bounds__(256) void softmax16_bf(unsigned short* __restrict__ oa, long total)
{
    const long t = (long)blockIdx.x * 256 + threadIdx.x;
    if (t >= total) return;
    unsigned short* p = oa + (t >> 2) * 192 + 128 + (t & 3) * 16;
    float v[16];
    float mx = -1e30f;
#pragma unroll
    for (int i = 0; i < 16; ++i) { v[i] = bf2f(p[i]); mx = fmaxf(mx, v[i]); }
    float s = 0.f;
#pragma unroll
    for (int i = 0; i < 16; ++i) { v[i] = __expf(v[i] - mx); s += v[i]; }
    const float inv = 1.0f / s;
#pragma unroll
    for (int i = 0; i < 16; ++i) p[i] = f2bf(v[i] * inv);
}

// ---------------- MS deformable attention: 2 q/wave, 8 ch/lane, fp16 val ----
__global__ __launch_bounds__(256) void msda8(const unsigned short* __restrict__ val,
                                             const unsigned short* __restrict__ oa,
                                             unsigned short* __restrict__ out)
{
    const int w = (blockIdx.x * 256 + threadIdx.x) >> 6;   // wave id < NB*LQ/2
    const int lane = threadIdx.x & 63;
    const int bq = w * 2 + (lane >> 5);
    const int h = (lane >> 3) & 3;
    const int c8 = (lane & 7) * 8;
    const int q = bq % LQ;
    const int b = bq / LQ;
    int Hq, bq0;
    if (q < 256)       { Hq = 16;  bq0 = 0; }
    else if (q < 1280) { Hq = 32;  bq0 = 256; }
    else if (q < 5376) { Hq = 64;  bq0 = 1280; }
    else               { Hq = 128; bq0 = 5376; }
    const int hw = q - bq0;
    const int qy = hw / Hq, qx = hw - qy * Hq;
    const float refx = ((float)qx + 0.5f) / (float)Hq;
    const float refy = ((float)qy + 0.5f) / (float)Hq;
    const unsigned short* oar = oa + (long)bq * 192;
    const int LH[4] = {16, 32, 64, 128};
    const int LB[4] = {0, 256, 1280, 5376};
    float a0 = 0.f, a1 = 0.f, a2 = 0.f, a3 = 0.f;
    float a4 = 0.f, a5 = 0.f, a6 = 0.f, a7 = 0.f;
#pragma unroll
    for (int lv = 0; lv < 4; ++lv) {
        const int Hl = LH[lv];
        const unsigned short* vb = val + ((long)b * LQ + LB[lv]) * 256 + h * 64 + c8;
#pragma unroll
        for (int p = 0; p < 4; ++p) {
            const unsigned int oxy = *(const unsigned int*)(oar + h * 32 + (lv * 4 + p) * 2);
            const float ox = bf2f((unsigned short)(oxy & 0xffffu));
            const float oy = bf2f((unsigned short)(oxy >> 16));
            const float wgt = bf2f(oar[128 + h * 16 + lv * 4 + p]);
            const float x = refx * (float)Hl + ox - 0.5f;
            const float y = refy * (float)Hl + oy - 0.5f;
            const float xf = floorf(x), yf = floorf(y);
            const float tx = x - xf, ty = y - yf;
            const int x0 = (int)xf, y0 = (int)yf;
            const float w00 = wgt * (1.f - ty) * (1.f - tx), w01 = wgt * (1.f - ty) * tx;
            const float w10 = wgt * ty * (1.f - tx),         w11 = wgt * ty * tx;
            const bool xv0 = (x0 >= 0) & (x0 < Hl);
            const bool xv1 = (x0 + 1 >= 0) & (x0 + 1 < Hl);
            // fp16 val -> v_fma_mix_f32 (f32 accumulate; unpack fused into FMA)
#define SAMPLE(WT, IDX) { const uint4 vv = *(const uint4*)(vb + (long)(IDX) * 256); \
        const __half2* ph = (const __half2*)&vv; \
        a0 += (WT) * __low2float(ph[0]); a1 += (WT) * __high2float(ph[0]); \
        a2 += (WT) * __low2float(ph[1]); a3 += (WT) * __high2float(ph[1]); \
        a4 += (WT) * __low2float(ph[2]); a5 += (WT) * __high2float(ph[2]); \
        a6 += (WT) * __low2float(ph[3]); a7 += (WT) * __high2float(ph[3]); }
            if (y0 >= 0 && y0 < Hl) {
                const int r = y0 * Hl;
                if (xv0) SAMPLE(w00, r + x0)
                if (xv1) SAMPLE(w01, r + x0 + 1)
            }
            if (y0 + 1 >= 0 && y0 + 1 < Hl) {
                const int r = (y0 + 1) * Hl;
                if (xv0) SAMPLE(w10, r + x0)
                if (xv1) SAMPLE(w11, r + x0 + 1)
            }
#undef SAMPLE
        }
    }
    unsigned int r0 = (unsigned int)f2bf(a0) | ((unsigned int)f2bf(a1) << 16);
    unsigned int r1 = (unsigned int)f2bf(a2) | ((unsigned int)f2bf(a3) << 16);
    unsigned int r2 = (unsigned int)f2bf(a4) | ((unsigned int)f2bf(a5) << 16);
    unsigned int r3 = (unsigned int)f2bf(a6) | ((unsigned int)f2bf(a7) << 16);
    uint4 o = make_uint4(r0, r1, r2, r3);
    *(uint4*)(out + (long)bq * 256 + h * 64 + c8) = o;
}

// ---------------- residual + layer-norm -> bf16 out -------------------------
__global__ __launch_bounds__(256) void ln_residual(const float* __restrict__ src,
                                                   const float* __restrict__ att,
                                                   unsigned short* __restrict__ outb,
                                                   const float* __restrict__ g,
                                                   const float* __restrict__ b)
{
    const long row = blockIdx.x;
    const int d = threadIdx.x;
    const long idx = row * 256 + d;
    const float v = src[idx] + att[idx];
    float s = wave_sum(v), sq = wave_sum(v * v);
    __shared__ float sh[8];
    const int wid = d >> 6, lane = d & 63;
    if (lane == 0) { sh[wid] = s; sh[4 + wid] = sq; }
    __syncthreads();
    const float S = sh[0] + sh[1] + sh[2] + sh[3];
    const float SQ = sh[4] + sh[5] + sh[6] + sh[7];
    const float m = S * (1.0f / 256.0f);
    const float var = SQ * (1.0f / 256.0f) - m * m;
    const float r = rsqrtf(var + 1e-5f);
    outb[idx] = f2bf((v - m) * r * g[d] + b[d]);
}

extern "C" void kernel_launch(void* const* d_in, const int* in_sizes, int n_in,
                              void* d_out, int out_size, void* d_ws, size_t ws_size,
                              hipStream_t stream)
{
    const float* x[4]  = {(const float*)d_in[0],  (const float*)d_in[5],
                          (const float*)d_in[10], (const float*)d_in[15]};
    const float* pw[4] = {(const float*)d_in[1],  (const float*)d_in[6],
                          (const float*)d_in[11], (const float*)d_in[16]};
    const float* pb[4] = {(const float*)d_in[2],  (const float*)d_in[7],
                          (const float*)d_in[12], (const float*)d_in[17]};
    const float* gg[4] = {(const float*)d_in[3],  (const float*)d_in[8],
                          (const float*)d_in[13], (const float*)d_in[18]};
    const float* gb[4] = {(const float*)d_in[4],  (const float*)d_in[9],
                          (const float*)d_in[14], (const float*)d_in[19]};
    const float* lvl_emb = (const float*)d_in[20];
    const float* Woff  = (const float*)d_in[21];
    const float* boff  = (const float*)d_in[22];
    const float* Wattn = (const float*)d_in[23];
    const float* battn = (const float*)d_in[24];
    const float* Wval  = (const float*)d_in[25];
    const float* bval  = (const float*)d_in[26];
    const float* Wout  = (const float*)d_in[27];
    const float* bout  = (const float*)d_in[28];
    const float* ng    = (const float*)d_in[29];
    const float* nbb   = (const float*)d_in[30];
    const float* W1    = (const float*)d_in[31];
    const float* b1    = (const float*)d_in[32];
    const float* W2    = (const float*)d_in[33];
    const float* b2    = (const float*)d_in[34];

    // ---- workspace layout (float offsets)
    const long M = (long)NB * LQ;                 // 43520
    const long SRC_F    = 0;                      // fp32 src        11,141,120 f
    const long SRCBF_F  = 11141120;               // bf16 src         5,570,560 f
    const long SHARED_F = SRCBF_F + 5570560;      // bf16 q/att/ln    5,570,560 f
    const long OA_F     = SHARED_F + 5570560;     // bf16 M*192       4,177,920 f
    const long POS_F    = OA_F + 4177920;         // bf16 LQ*256      2,785,280 f
    const long WT_F     = POS_F + 2785280;        // bf16 weights     1,056,768 f
    const long BIAS_F   = WT_F + 1056768;         // 576 f
    const long STATS_F  = BIAS_F + 576;           // 512 f
    const long NEED_F   = STATS_F + 512;          // 30,303,296 f = 121.2 MB
    if (ws_size < (size_t)NEED_F * sizeof(float)) return;

    float* ws = (float*)d_ws;
    float*          src    = ws + SRC_F;
    unsigned short* src_bf = (unsigned short*)(ws + SRCBF_F);
    unsigned short* shbf   = (unsigned short*)(ws + SHARED_F);
    unsigned short* oab    = (unsigned short*)(ws + OA_F);
    unsigned short* posbf  = (unsigned short*)(ws + POS_F);
    unsigned short* wT     = (unsigned short*)(ws + WT_F);
    float*          biasoa = ws + BIAS_F;
    float*          stats  = ws + STATS_F;
    // conv-phase overlays: zbuf needs max 2*16384*256 = 8,388,608 f in SHARED+OA;
    // pw_bf (983,040 ushorts = 491,520 f) lives in the tail of OA after zbuf.
    float*          zbuf   = ws + SHARED_F;
    unsigned short* pwbf   = (unsigned short*)(ws + SHARED_F + 8388608);
    float*          Bbuf   = (float*)d_out;       // xT / val / attn-proj scratch

    // bf16 transposed weight offsets (ushort units)
    const long OAT = 0;                 // 3 * 192*256
    const long VALT = OAT + 3 * 49152;  // 3 * 65536
    const long OUTT = VALT + 3 * 65536;
    const long W1T = OUTT + 3 * 65536;  // 3 * 1024*256
    const long W2T = W1T + 3 * 262144;  // 3 * 256*1024

    zero_buf<<<2, 256, 0, stream>>>(stats, 512);
    bias_cat<<<3, 256, 0, stream>>>(boff, battn, biasoa);
    pos_kernel<<<LQ, 256, 0, stream>>>(posbf, lvl_emb);
    for (int l = 0; l < 3; ++l) {
        transpose_cvt<<<dim3(4, 8),  256, 0, stream>>>(Woff + (long)l * 32768,  wT + OAT + l * 49152, 256, 128);
        transpose_cvt<<<dim3(2, 8),  256, 0, stream>>>(Wattn + (long)l * 16384, wT + OAT + l * 49152 + 128 * 256, 256, 64);
        transpose_cvt<<<dim3(8, 8),  256, 0, stream>>>(Wval + (long)l * 65536,  wT + VALT + l * 65536, 256, 256);
        transpose_cvt<<<dim3(8, 8),  256, 0, stream>>>(Wout + (long)l * 65536,  wT + OUTT + l * 65536, 256, 256);
        transpose_cvt<<<dim3(32, 8), 256, 0, stream>>>(W1 + (long)l * 262144,   wT + W1T + l * 262144, 256, 1024);
        transpose_cvt<<<dim3(8, 32), 256, 0, stream>>>(W2 + (long)l * 262144,   wT + W2T + l * 262144, 1024, 256);
    }

    // pw -> bf16 (already N x K layout)
    const int LC[4] = {2048, 1024, 512, 256};
    long pwoff[4];
    {
        long o = 0;
        for (int lv = 0; lv < 4; ++lv) { pwoff[lv] = o; o += (long)LC[lv] * 256; }
    }
    for (int lv = 0; lv < 4; ++lv)
        cvt_bf<<<(int)((LC[lv] * 256 + 255) / 256), 256, 0, stream>>>(
            pw[lv], pwbf + pwoff[lv], (long)LC[lv] * 256);

    const int LHW[4]   = {256, 1024, 4096, 16384};
    const int LSH[4]   = {8, 10, 12, 14};
    const int LBASE[4] = {0, 256, 1280, 5376};
    for (int lv = 0; lv < 4; ++lv) {
        const int HW = LHW[lv], C = LC[lv];
        // xT (B*HW, C) bf16 in d_out scratch
        transpose_cvt_x<<<dim3(HW / 32, C / 32, NB), 256, 0, stream>>>(
            x[lv], (unsigned short*)Bbuf, C, HW);
        // z (B*HW, 256) fp32 = xT @ pw^T + pb
        gemm_bf<128><<<dim3(2, NB * HW / 128), 256, 0, stream>>>(
            (const unsigned short*)Bbuf, pwbf + pwoff[lv], C,
            zbuf, nullptr, 256, pb[lv], 0, 0, nullptr, nullptr);
        gn_stats2<<<dim3(HW / 64, NB), 256, 0, stream>>>(zbuf, stats + lv * 128, HW, 64);
        const long total4 = (long)NB * HW * 64;
        gn_scale<<<(int)((total4 + 255) / 256), 256, 0, stream>>>(
            zbuf, src, src_bf, stats + lv * 128, gg[lv], gb[lv],
            LSH[lv], LBASE[lv], total4);
    }

    for (int l = 0; l < 3; ++l) {
        // q for layer 0 (layers 1,2 get q fused from previous FFN2 epilogue)
        if (l == 0)
            make_q2<<<10880, 256, 0, stream>>>(src_bf, posbf, shbf, M * 64);
        // off+attn combined: (M,256)@(256,192) -> oab bf16
        gemm_bf<64><<<dim3(3, 340), 256, 0, stream>>>(
            shbf, wT + OAT + (long)l * 49152, 256, nullptr, oab, 192,
            biasoa + l * 192, 0, 0, nullptr, nullptr);
        softmax16_bf<<<680, 256, 0, stream>>>(oab, M * 4);
        // value proj: src_bf @ Wval^T -> Bbuf fp16
        gemm_bf<128><<<dim3(2, 340), 256, 0, stream>>>(
            src_bf, wT + VALT + (long)l * 65536, 256, nullptr, (unsigned short*)Bbuf, 256,
            bval + l * 256, 0, 1, nullptr, nullptr);
        // sampling -> shbf bf16 (q dead); 2 queries per wave
        msda8<<<5440, 256, 0, stream>>>((const unsigned short*)Bbuf, oab, shbf);
        // output proj: shbf @ Wout^T -> Bbuf fp32 (val dead)
        gemm_bf<128><<<dim3(2, 340), 256, 0, stream>>>(
            shbf, wT + OUTT + (long)l * 65536, 256, Bbuf, nullptr, 256,
            bout + l * 256, 0, 0, nullptr, nullptr);
        // residual + LN -> shbf bf16 (att dead)
        ln_residual<<<(int)M, 256, 0, stream>>>(src, Bbuf, shbf, ng + l * 256, nbb + l * 256);
        // FFN in halves; hidden bf16 lives in d_out (l<2) or dead src (l==2)
        unsigned short* hid = (l < 2) ? (unsigned short*)d_out : (unsigned short*)src;
        for (int hf = 0; hf < 2; ++hf) {
            const long r0 = (long)hf * (M / 2);
            gemm_bf<128><<<dim3(8, 170), 256, 0, stream>>>(
                shbf + r0 * 256, wT + W1T + (long)l * 262144, 256,
                nullptr, hid, 1024, b1 + l * 1024, 1, 0, nullptr, nullptr);
            float* cf = ((l < 2) ? src : (float*)d_out) + r0 * 256;
            unsigned short* cb = (l < 2) ? (src_bf + r0 * 256) : nullptr;
            // for l<2: fuse next layer's q = out + pos into epilogue.
            // M/2 == LQ, so local row == pos row for both batch halves.
            unsigned short* cq = (l < 2) ? (shbf + r0 * 256) : nullptr;
            gemm_bf<128><<<dim3(2, 170), 256, 0, stream>>>(
                hid, wT + W2T + (long)l * 262144, 1024,
                cf, cb, 256, b2 + l * 256, 0, 0, cq, posbf);
        }
    }
}